// Round 1
// 583.926 us; speedup vs baseline: 1.0118x; 1.0118x over previous
//
#include <hip/hip_runtime.h>
#include <math.h>

// ============================================================================
// acsasrec_decode2 v5: v4.1 + T2 XOR-swizzle on kloop LDS tiles.
//  - kloop staged tiles are [128][32] bf16 (64B rows). Old fragment reads
//    (row*64 + quad*16) were a 4-way bank conflict per 8-lane group
//    (SQ_LDS_BANK_CONFLICT = 4.19M on FFN1). Fix: XOR 16B-slot with
//    (row>>1)&3 on BOTH sides (pre-swizzled global source for
//    global_load_lds, swizzled ds_read column) -> conflict-free b128 reads.
//  - vres harvest reads get the matching inverse mapping.
//  - Everything else identical to v4.1 (10 dispatches).
// ============================================================================

typedef unsigned short u16;
typedef __attribute__((ext_vector_type(8))) short bf16x8;
typedef __attribute__((ext_vector_type(4))) float f32x4;

#define NM 16384        // B*S tokens

__device__ __forceinline__ u16 f2b(float f) {
  union { float f; unsigned u; } x; x.f = f;
  return (u16)((x.u + 0x7fffu + ((x.u >> 16) & 1u)) >> 16);  // RNE
}
__device__ __forceinline__ float b2f(u16 u) {
  union { unsigned u; float f; } x; x.u = ((unsigned)u) << 16; return x.f;
}
__device__ __forceinline__ f32x4 mfma16(bf16x8 a, bf16x8 b, f32x4 c) {
  return __builtin_amdgcn_mfma_f32_16x16x32_bf16(a, b, c, 0, 0, 0);
}
// async global->LDS, 16B/lane; LDS dest = wave-uniform base + lane*16.
__device__ __forceinline__ void gl16(const u16* g, u16* l) {
  __builtin_amdgcn_global_load_lds(
      (const __attribute__((address_space(1))) unsigned int*)(const void*)g,
      (__attribute__((address_space(3))) unsigned int*)(void*)l, 16, 0, 0);
}
__device__ __forceinline__ bf16x8 baddv(bf16x8 a, bf16x8 b) {
  bf16x8 r;
  #pragma unroll
  for (int e = 0; e < 8; ++e) r[e] = (short)f2b(b2f((u16)a[e]) + b2f((u16)b[e]));
  return r;
}

// ---------------- BK=32 K-loop (round-2 structure + T2 swizzle) -------------
// LDS layout: linear [128][32] bf16; 16B slot s of row r holds global chunk
// g = s ^ ((r>>1)&3). Staged via pre-swizzled global source (global_load_lds
// dest must stay linear); fragment reads use slot = quad ^ ((row>>1)&3).
// If vres: acc[i][j] += A-element at (row, col=gn) harvested from staged LDS
// tile when the k-window covers this block's output columns (value residual).
__device__ __forceinline__ void kloop(
    const u16* __restrict__ A, const u16* __restrict__ W,
    int m0, int n0, int K, int kiters, u16* As, u16* Bs, bool vres,
    f32x4 (&acc)[4][4])
{
  const int tid = threadIdx.x;
  const int wave = tid>>6, lane = tid&63, quad = lane>>4, l16 = lane&15;
  const int wm = wave>>1, wn = wave&1;
  const int r1 = tid>>2;
  const int ch1 = (((tid&3) ^ ((r1>>1)&3)) << 3);  // swizzled source chunk (elems)
  const int qsw = ((quad ^ ((l16>>1)&3)) << 3);    // swizzled read column (elems)
  const u16* pA = A + (size_t)(m0+r1)*K + ch1;
  const u16* pB = W + (size_t)(n0+r1)*K + ch1;
  u16* sa = As + tid*8;  u16* sb = Bs + tid*8;
  for (int it = 0; it < kiters; ++it) {
    const int k0 = it*32;
    gl16(pA + k0, sa); gl16(pA + (size_t)64*K + k0, sa + 2048);
    gl16(pB + k0, sb); gl16(pB + (size_t)64*K + k0, sb + 2048);
    __syncthreads();
    bf16x8 af[4], bf[4];
    #pragma unroll
    for (int i = 0; i < 4; ++i)
      af[i] = *(const bf16x8*)&As[(wm*64 + i*16 + l16)*32 + qsw];
    #pragma unroll
    for (int j = 0; j < 4; ++j)
      bf[j] = *(const bf16x8*)&Bs[(wn*64 + j*16 + l16)*32 + qsw];
    if (vres) {     // value residual from staged A-tile (N==K==512 space)
      #pragma unroll
      for (int j = 0; j < 4; ++j) {
        const int start = n0 + wn*64 + j*16;
        if ((start & ~31) == k0) {
          const int c = (start & 31) + l16;
          #pragma unroll
          for (int i = 0; i < 4; ++i)
            #pragma unroll
            for (int rr = 0; rr < 4; ++rr) {
              const int rw = wm*64 + i*16 + quad*4 + rr;
              const int sw = ((((c>>3) ^ ((rw>>1)&3)) << 3) | (c & 7));
              acc[i][j][rr] += b2f(As[rw*32 + sw]);
            }
        }
      }
    }
    #pragma unroll
    for (int i = 0; i < 4; ++i)
      #pragma unroll
      for (int j = 0; j < 4; ++j)
        acc[i][j] = mfma16(af[i], bf[j], acc[i][j]);
    __syncthreads();
  }
}

// ---------------- standard epilogue: acc -> LDS bf16 tile -> 16B stores -----
// out[M,N] bf16; v = (acc + bias [gelu]) [+ex] * scale.
// exmode: 0 none | 1 ex[(gr%512)*512+gc] | 2 ex[gr*512+gc]  (ex is bf16)
__device__ __forceinline__ void epi_std(
    f32x4 (&acc)[4][4], const float* __restrict__ bias,
    const u16* __restrict__ ex, int exmode, float scale, int gelu,
    u16* __restrict__ out, int m0, int n0, int N, u16* til)
{
  const int tid = threadIdx.x;
  const int wave = tid>>6, lane = tid&63, quad = lane>>4, l16 = lane&15;
  const int wm = wave>>1, wn = wave&1;
  #pragma unroll
  for (int pass = 0; pass < 2; ++pass) {
    if (wm == pass) {
      #pragma unroll
      for (int j = 0; j < 4; ++j) {
        const int c = wn*64 + j*16 + l16;
        const float bv = bias[n0 + c];
        #pragma unroll
        for (int i = 0; i < 4; ++i)
          #pragma unroll
          for (int rr = 0; rr < 4; ++rr) {
            float v = acc[i][j][rr] + bv;
            if (gelu) v = 0.5f*v*(1.0f + erff(v*0.70710678118654752f));
            til[(i*16 + quad*4 + rr)*136 + c] = f2b(v);
          }
      }
    }
    __syncthreads();
    const int r = tid>>2, ck = tid&3;
    const int gr = m0 + pass*64 + r;
    #pragma unroll
    for (int kk = 0; kk < 4; ++kk) {
      const int cc = ck*32 + kk*8, gc = n0 + cc;
      u16 e8[8];
      *(uint4*)e8 = *(const uint4*)&til[r*136 + cc];
      if (exmode) {
        const u16* ep = (exmode == 1) ? &ex[(size_t)(gr & 511)*512 + gc]
                                      : &ex[(size_t)gr*512 + gc];
        #pragma unroll
        for (int e = 0; e < 8; ++e) e8[e] = f2b((b2f(e8[e]) + b2f(ep[e]))*scale);
      } else if (scale != 1.0f) {
        #pragma unroll
        for (int e = 0; e < 8; ++e) e8[e] = f2b(b2f(e8[e])*scale);
      }
      *(uint4*)&out[(size_t)gr*N + gc] = *(uint4*)e8;
    }
    __syncthreads();
  }
}

// ---------------- V epilogue: transposed store -> Vt[B*8*64, 512] ----------
__device__ __forceinline__ void epi_vt(
    f32x4 (&acc)[4][4], const float* __restrict__ bias,
    u16* __restrict__ Vt, int m0, int n0, u16* til)
{
  const int tid = threadIdx.x;
  const int wave = tid>>6, lane = tid&63, quad = lane>>4, l16 = lane&15;
  const int wm = wave>>1, wn = wave&1;
  const int b = m0 >> 9, s0 = m0 & 511;
  #pragma unroll
  for (int pass = 0; pass < 2; ++pass) {
    if (wn == pass) {
      #pragma unroll
      for (int j = 0; j < 4; ++j) {
        const int cl = j*16 + l16;                 // 0..63
        const float bv = bias[n0 + pass*64 + cl];
        #pragma unroll
        for (int i = 0; i < 4; ++i)
          #pragma unroll
          for (int rr = 0; rr < 4; ++rr)
            til[cl*136 + wm*64 + i*16 + quad*4 + rr] = f2b(acc[i][j][rr] + bv);
      }
    }
    __syncthreads();
    const int cl = tid>>2, ck = tid&3;
    const int gn = n0 + pass*64 + cl, h = gn>>6, d = gn&63;
    u16* orow = Vt + ((size_t)((b*8 + h)*64 + d))*512 + s0 + ck*32;
    #pragma unroll
    for (int kk = 0; kk < 4; ++kk)
      *(uint4*)&orow[kk*8] = *(const uint4*)&til[cl*136 + ck*32 + kk*8];
    __syncthreads();
  }
}

// ---------------- projection kernel (7 phases, N=K=512) ----------------
// phases: 0 q(x@Wq *0.125) 1 k(x@Wk) 2 p(bb@.5Wbq +PQs, *0.125)
//         3 m(bb@.5Wbk +PKs) 4 v(vb@Wv +vb residual -> Vt transposed)
//         5 posq(pos@Wpq *0.5 -> PQs) 6 posk(pos@Wpk *0.5 -> PKs)
struct PJ { const u16* A; const u16* W; const float* bias; const u16* ex;
            u16* out; float scale; int exmode; int epiv; };
struct ProjArgs { PJ p[7]; };

__global__ __launch_bounds__(256, 2) void proj_kernel(ProjArgs pa, int phaseBase) {
  __shared__ __align__(16) u16 smem[8704];   // As(4096) Bs(4096); til(8704) reuse
  u16* As = smem;  u16* Bs = smem + 4096;
  const PJ P = pa.p[phaseBase + (blockIdx.x >> 2)];
  const int n0 = (blockIdx.x & 3)*128, m0 = blockIdx.y*128;
  f32x4 acc[4][4] = {};
  kloop(P.A, P.W, m0, n0, 512, 16, As, Bs, P.epiv != 0, acc);
  if (P.epiv) epi_vt(acc, P.bias, P.out, m0, n0, smem);
  else        epi_std(acc, P.bias, P.ex, P.exmode, P.scale, 0, P.out, m0, n0, 512, smem);
}

// ---------------- single GEMM (d-proj, FFN1, FFN2) ----------------
template<int GELU>
__global__ __launch_bounds__(256, 2) void gemm1_kernel(
    const u16* __restrict__ A, const u16* __restrict__ W,
    const float* __restrict__ bias, u16* __restrict__ out, int N, int K)
{
  __shared__ __align__(16) u16 smem[8704];
  const int m0 = blockIdx.y*128, n0 = blockIdx.x*128;
  f32x4 acc[4][4] = {};
  kloop(A, W, m0, n0, K, K>>5, smem, smem + 4096, false, acc);
  epi_std(acc, bias, nullptr, 0, 1.0f, GELU, out, m0, n0, N, smem);
}

// ---------------- cast f32 -> bf16 (all inputs) ----------------
__global__ __launch_bounds__(256) void cast_all_kernel(
    const float* __restrict__ x, const float* __restrict__ v,
    const float* __restrict__ be, const float* __restrict__ pos,
    u16* __restrict__ xb, u16* __restrict__ vb, u16* __restrict__ bb,
    u16* __restrict__ posb)
{
  int z = blockIdx.y;
  const float* in = (z==0) ? x : (z==1) ? v : (z==2) ? be : pos;
  u16* out = (z==0) ? xb : (z==1) ? vb : (z==2) ? bb : posb;
  int n4 = (z < 3) ? (NM*512/4) : (512*512/4);
  int i = blockIdx.x*256 + threadIdx.x;
  if (i >= n4) return;
  float4 w = ((const float4*)in)[i];
  ((ushort4*)out)[i] = make_ushort4(f2b(w.x), f2b(w.y), f2b(w.z), f2b(w.w));
}

// ---------------- weight prep: transpose+cast 10 weights + biases ----------
struct PrepArgs {
  const float* w[10];  // Wq Wk Wv Wpk Wpq Wbk Wbq Wd W1 W2
  u16* o[10];
  const float* bbq; const float* bbk;
  float* Bq2; float* Bk2;
};
__global__ __launch_bounds__(256) void wprep_all_kernel(PrepArgs a) {
  int job = blockIdx.x;
  if (job == 1024) {   // Bq2 = 0.5*bbq ; Bk2 = 0.5*bbk
    for (int i = threadIdx.x; i < 512; i += 256) {
      a.Bq2[i] = 0.5f*a.bbq[i];
      a.Bk2[i] = 0.5f*a.bbk[i];
    }
    return;
  }
  int wsel, n0, k0, K, N;
  if (job < 512)      { wsel = job>>6; int t = job&63;  n0=(t&7)*64;  k0=(t>>3)*64; K=512;  N=512; }
  else if (job < 768) { wsel = 8;      int t = job-512; n0=(t&31)*64; k0=(t>>5)*64; K=512;  N=2048; }
  else                { wsel = 9;      int t = job-768; n0=(t&7)*64;  k0=(t>>3)*64; K=2048; N=512; }
  float sc = (wsel == 5 || wsel == 6) ? 0.5f : 1.0f;    // Wbk, Wbq pre-scaled
  const float* in = a.w[wsel];
  u16* out = a.o[wsel];
  __shared__ __align__(16) u16 til[64*72];
  for (int idx = threadIdx.x; idx < 4096; idx += 256) {
    int r = idx>>6, c = idx&63;
    til[r*72+c] = f2b(in[(size_t)(k0+r)*N + n0+c] * sc);
  }
  __syncthreads();
  for (int idx = threadIdx.x; idx < 4096; idx += 256) {
    int r = idx>>6, c = idx&63;
    out[(size_t)(n0+r)*K + k0+c] = til[c*72+r];
  }
}

// ---------------- flash attention v4 ----------------
// grid (qh=2, h=8, b=32); 512 threads; 2 q-strips/wave = 256 q-rows/block.
// Q-frags: [q+p | q] combined in-register from Qraw/Praw (both pre-scaled /8).
// K-LDS: [k | m] staged from Kraw/Mraw. No-max softmax (masked = exp*1e-30).
__global__ __launch_bounds__(512, 2) void attn_kernel(
    const u16* __restrict__ Qraw, const u16* __restrict__ Praw,
    const u16* __restrict__ Kraw, const u16* __restrict__ Mraw,
    const u16* __restrict__ Vt, const int* __restrict__ iseq,
    u16* __restrict__ ctx)
{
  const int qh = blockIdx.x, h = blockIdx.y, b = blockIdx.z;
  const int tid = threadIdx.x;
  const int wave = tid>>6, lane = tid&63, quad = lane>>4, l16 = lane&15;

  __shared__ __align__(16) u16 Ks[2][64*136];
  __shared__ __align__(16) u16 Vs[2][64*72];
  __shared__ __align__(16) u16 Ps[8][16*72];
  __shared__ float sel[512];

  const int q0 = qh*256;
  const int ntiles = 4*qh + 4;
  const u16* Kg = Kraw + (size_t)(b*512)*512 + h*64;
  const u16* Mg = Mraw + (size_t)(b*512)*512 + h*64;
  const u16* Vg = Vt + (size_t)((b*8 + h)*64)*512;

  if (tid < 512) sel[tid] = (iseq[b*512 + tid] > 0) ? 1.0f : 1e-30f;

  bf16x8 aq[2][4];
  #pragma unroll
  for (int s = 0; s < 2; ++s) {
    const size_t ro = (size_t)(b*512 + q0 + s*128 + wave*16 + l16)*512 + h*64;
    bf16x8 qf0 = *(const bf16x8*)&Qraw[ro + quad*8];
    bf16x8 qf1 = *(const bf16x8*)&Qraw[ro + 32 + quad*8];
    bf16x8 pf0 = *(const bf16x8*)&Praw[ro + quad*8];
    bf16x8 pf1 = *(const bf16x8*)&Praw[ro + 32 + quad*8];
    aq[s][0] = baddv(qf0, pf0); aq[s][1] = baddv(qf1, pf1);
    aq[s][2] = qf0;             aq[s][3] = qf1;
  }

  const int sr = tid>>3, sc8 = (tid&7)*8;
  uint4 kreg = *(const uint4*)&Kg[(size_t)sr*512 + sc8];
  uint4 mreg = *(const uint4*)&Mg[(size_t)sr*512 + sc8];
  uint4 vreg = *(const uint4*)&Vg[(size_t)sr*512 + sc8];

  f32x4 Ob[2][4] = {};
  float lrow[2][4] = {};
  u16* Pw = Ps[wave];
  int buf = 0;

  for (int kt = 0; kt < ntiles; ++kt) {
    const int k0 = kt*64;
    *(uint4*)&Ks[buf][sr*136 + sc8]      = kreg;
    *(uint4*)&Ks[buf][sr*136 + 64 + sc8] = mreg;
    *(uint4*)&Vs[buf][sr*72 + sc8]       = vreg;
    __syncthreads();
    if (kt + 1 < ntiles) {
      const int kn = k0 + 64;
      kreg = *(const uint4*)&Kg[(size_t)(kn + sr)*512 + sc8];
      mreg = *(const uint4*)&Mg[(size_t)(kn + sr)*512 + sc8];
      vreg = *(const uint4*)&Vg[(size_t)sr*512 + kn + sc8];
    }
    const bool act0 = (q0 + wave*16 + 15) >= k0;
    const bool act1 = (q0 + 128 + wave*16 + 15) >= k0;
    if (act1) {
      f32x4 sc[2][4] = {};
      #pragma unroll
      for (int ks = 0; ks < 4; ++ks) {
        bf16x8 bk[4];
        #pragma unroll
        for (int j = 0; j < 4; ++j)
          bk[j] = *(const bf16x8*)&Ks[buf][(j*16 + l16)*136 + ks*32 + quad*8];
        if (act0) {
          #pragma unroll
          for (int j = 0; j < 4; ++j) sc[0][j] = mfma16(aq[0][ks], bk[j], sc[0][j]);
        }
        #pragma unroll
        for (int j = 0; j < 4; ++j) sc[1][j] = mfma16(aq[1][ks], bk[j], sc[1][j]);
      }
      #pragma unroll
      for (int s = 0; s < 2; ++s) {
        if (s == 0 && !act0) continue;
        const int rb = q0 + s*128 + wave*16 + quad*4;
        float pj[4][4];
        #pragma unroll
        for (int j = 0; j < 4; ++j) {
          int col = k0 + j*16 + l16;
          float fs = sel[col];
          #pragma unroll
          for (int r = 0; r < 4; ++r) {
            float m2 = (col <= rb + r) ? fs : 1e-30f;
            pj[j][r] = __expf(sc[s][j][r]) * m2;
          }
        }
        #pragma unroll
        for (int r = 0; r < 4; ++r)
          lrow[s][r] += pj[0][r] + pj[1][r] + pj[2][r] + pj[3][r];
        #pragma unroll
        for (int j = 0; j < 4; ++j)
          #pragma unroll
          for (int r = 0; r < 4; ++r)
            Pw[(quad*4 + r)*72 + j*16 + l16] = f2b(pj[j][r]);
        #pragma unroll
        for (int c = 0; c < 4; ++c) {
          #pragma unroll
          for (int k2 = 0; k2 < 2; ++k2) {
            bf16x8 ap = *(const bf16x8*)&Pw[l16*72 + k2*32 + quad*8];
            bf16x8 bv = *(const bf16x8*)&Vs[buf][(c*16 + l16)*72 + k2*32 + quad*8];
            Ob[s][c] = mfma16(ap, bv, Ob[s][c]);
          }
        }
      }
    }
    buf ^= 1;
  }

  #pragma unroll
  for (int s = 0; s < 2; ++s) {
    #pragma unroll
    for (int r = 0; r < 4; ++r) {
      float l = lrow[s][r];
      #pragma unroll
      for (int d2 = 1; d2 < 16; d2 <<= 1) l += __shfl_xor(l, d2, 64);
      float inv = 1.0f / l;
      int grow = b*512 + q0 + s*128 + wave*16 + quad*4 + r;
      #pragma unroll
      for (int c = 0; c < 4; ++c)
        ctx[(size_t)grow*512 + h*64 + c*16 + l16] = f2b(Ob[s][c][r]*inv);
    }
  }
}

// ---------------- LayerNorm over H=512 (bf16 main input) ----------------
// RES: 0 = f32 residual, 1 = bf16 residual.
template<int RES>
__global__ __launch_bounds__(256) void ln_kernel(
    const u16* __restrict__ a, const void* __restrict__ resv,
    const float* __restrict__ g, const float* __restrict__ be,
    float* __restrict__ of, u16* __restrict__ ob)
{
  const int wave = threadIdx.x >> 6, lane = threadIdx.x & 63;
  const int row = blockIdx.x*4 + wave;
  const ushort4* pa = (const ushort4*)(a + (size_t)row*512);
  ushort4 a0 = pa[lane], a1 = pa[lane+64];
  float v[8] = { b2f(a0.x), b2f(a0.y), b2f(a0.z), b2f(a0.w),
                 b2f(a1.x), b2f(a1.y), b2f(a1.z), b2f(a1.w) };
  if (RES == 1) {
    const ushort4* pr = (const ushort4*)((const u16*)resv + (size_t)row*512);
    ushort4 u0 = pr[lane], u1 = pr[lane+64];
    v[0]+=b2f(u0.x); v[1]+=b2f(u0.y); v[2]+=b2f(u0.z); v[3]+=b2f(u0.w);
    v[4]+=b2f(u1.x); v[5]+=b2f(u1.y); v[6]+=b2f(u1.z); v[7]+=b2f(u1.w);
  } else {
    const float4* pr = (const float4*)((const float*)resv + (size_t)row*512);
    float4 r0 = pr[lane], r1 = pr[lane+64];
    v[0]+=r0.x; v[1]+=r0.y; v[2]+=r0.z; v[3]+=r0.w;
    v[4]+=r1.x; v[5]+=r1.y; v[6]+=r1.z; v[7]+=r1.w;
  }
  float s = 0.f, q = 0.f;
  #pragma unroll
  for (int e = 0; e < 8; ++e) { s += v[e]; q += v[e]*v[e]; }
  #pragma unroll
  for (int d = 1; d < 64; d <<= 1) { s += __shfl_xor(s, d, 64); q += __shfl_xor(q, d, 64); }
  float mean = s * (1.0f/512.0f);
  float var  = q * (1.0f/512.0f) - mean*mean;
  float rstd = rsqrtf(var + 1e-12f);
  float4 g0 = ((const float4*)g)[lane],  g1 = ((const float4*)g)[lane+64];
  float4 b0 = ((const float4*)be)[lane], b1 = ((const float4*)be)[lane+64];
  float o[8];
  o[0]=(v[0]-mean)*rstd*g0.x+b0.x; o[1]=(v[1]-mean)*rstd*g0.y+b0.y;
  o[2]=(v[2]-mean)*rstd*g0.z+b0.z; o[3]=(v[3]-mean)*rstd*g0.w+b0.w;
  o[4]=(v[4]-mean)*rstd*g1.x+b1.x; o[5]=(v[5]-mean)*rstd*g1.y+b1.y;
  o[6]=(v[6]-mean)*rstd*g1.z+b1.z; o[7]=(v[7]-mean)*rstd*g1.w+b1.w;
  if (of) {
    ((float4*)(of + (size_t)row*512))[lane]    = make_float4(o[0],o[1],o[2],o[3]);
    ((float4*)(of + (size_t)row*512))[lane+64] = make_float4(o[4],o[5],o[6],o[7]);
  }
  if (ob) {
    ((ushort4*)(ob + (size_t)row*512))[lane]    = make_ushort4(f2b(o[0]),f2b(o[1]),f2b(o[2]),f2b(o[3]));
    ((ushort4*)(ob + (size_t)row*512))[lane+64] = make_ushort4(f2b(o[4]),f2b(o[5]),f2b(o[6]),f2b(o[7]));
  }
}

// ============================================================================
extern "C" void kernel_launch(void* const* d_in, const int* in_sizes, int n_in,
                              void* d_out, int out_size, void* d_ws, size_t ws_size,
                              hipStream_t stream) {
  (void)in_sizes; (void)n_in; (void)out_size; (void)ws_size;
  const float* x    = (const float*)d_in[0];
  const float* vin  = (const float*)d_in[1];
  const float* beh  = (const float*)d_in[2];
  const float* pos  = (const float*)d_in[3];
  const float* bq   = (const float*)d_in[5];
  const float* bk   = (const float*)d_in[7];
  const float* bv   = (const float*)d_in[9];
  const float* bpk  = (const float*)d_in[11];
  const float* bpq  = (const float*)d_in[13];
  const float* bbk  = (const float*)d_in[15];
  const float* bbq  = (const float*)d_in[17];
  const float* bd   = (const float*)d_in[19];
  const float* ln_g = (const float*)d_in[20];
  const float* ln_b = (const float*)d_in[21];
  const float* b1   = (const float*)d_in[23];
  const float* b2   = (const float*)d_in[25];
  const float* ln2_g= (const float*)d_in[26];
  const float* ln2_b= (const float*)d_in[27];
  const int*   iseq = (const int*)d_in[28];
  float* out = (float*)d_out;
  char* ws = (char*)d_ws;

  // ---- workspace (~145 MB) ----
  size_t off = 0;
  auto nxt = [&](size_t sz) { size_t r = off; off += (sz + 255) & ~(size_t)255; return r; };
  size_t oWT[8]; for (int i = 0; i < 8; ++i) oWT[i] = nxt(512*512*2);
  size_t oW1T = nxt((size_t)512*2048*2);
  size_t oW2T = nxt((size_t)512*2048*2);
  size_t oBq2 = nxt(512*4);
  size_t oBk2 = nxt(512*4);
  size_t oPb  = nxt(512*512*2);
  size_t oPQ  = nxt(512*512*2);           // PQs bf16
  size_t oPK  = nxt(512*512*2);           // PKs bf16
  size_t oXb  = nxt((size_t)NM*512*2);    // xb; dead after proj, reused as ab
  size_t oVb  = nxt((size_t)NM*512*2);    // vb; dead after proj, reused as Cb
  size_t oBb  = nxt((size_t)NM*512*2);    // bb
  size_t oQr  = nxt((size_t)NM*512*2);    // Qraw  (Qr..Mr contiguous 134MB; h1b after attn)
  size_t oPr  = nxt((size_t)NM*512*2);    // Praw
  size_t oKr  = nxt((size_t)NM*512*2);    // Kraw
  size_t oMr  = nxt((size_t)NM*512*2);    // Mraw
  size_t oVt  = nxt((size_t)NM*512*2);    // Vt; dead after attn, reused as f2

  u16* WT[8]; for (int i = 0; i < 8; ++i) WT[i] = (u16*)(ws + oWT[i]);
  u16*   W1T  = (u16*)(ws + oW1T);
  u16*   W2T  = (u16*)(ws + oW2T);
  float* Bq2  = (float*)(ws + oBq2);
  float* Bk2  = (float*)(ws + oBk2);
  u16*   posb = (u16*)(ws + oPb);
  u16*   PQs  = (u16*)(ws + oPQ);
  u16*   PKs  = (u16*)(ws + oPK);
  u16*   xb   = (u16*)(ws + oXb);
  u16*   vb   = (u16*)(ws + oVb);
  u16*   bb   = (u16*)(ws + oBb);
  u16*   Qraw = (u16*)(ws + oQr);
  u16*   Praw = (u16*)(ws + oPr);
  u16*   Kraw = (u16*)(ws + oKr);
  u16*   Mraw = (u16*)(ws + oMr);
  u16*   Vtb  = (u16*)(ws + oVt);
  u16*   Cb   = (u16*)(ws + oVb);   // alias: vb dead after proj
  u16*   db   = (u16*)(ws + oPr);   // alias: Praw dead after attn (LN1 reads before FFN1 writes h1b)
  u16*   ab   = (u16*)(ws + oXb);   // alias: xb dead after proj
  u16*   h1b  = (u16*)(ws + oQr);   // alias: Qraw..Mraw dead after attn (67 MB)
  u16*   f2   = (u16*)(ws + oVt);   // alias: Vt dead after attn

  // 1. casts
  cast_all_kernel<<<dim3(8192, 4), 256, 0, stream>>>(x, vin, beh, pos, xb, vb, bb, posb);
  // 2. weight prep + combined biases
  PrepArgs pr;
  const int wi[10] = {4, 6, 8, 10, 12, 14, 16, 18, 22, 24};
  for (int i = 0; i < 10; ++i) pr.w[i] = (const float*)d_in[wi[i]];
  for (int i = 0; i < 8; ++i)  pr.o[i] = WT[i];
  pr.o[8] = W1T; pr.o[9] = W2T;
  pr.bbq = bbq; pr.bbk = bbk; pr.Bq2 = Bq2; pr.Bk2 = Bk2;
  wprep_all_kernel<<<1025, 256, 0, stream>>>(pr);
  // phase table
  ProjArgs pj;
  pj.p[0] = { xb,   WT[0], bq,   nullptr, Qraw, 0.125f, 0, 0 };
  pj.p[1] = { xb,   WT[1], bk,   nullptr, Kraw, 1.0f,   0, 0 };
  pj.p[2] = { bb,   WT[6], Bq2,  PQs,     Praw, 0.125f, 1, 0 };
  pj.p[3] = { bb,   WT[5], Bk2,  PKs,     Mraw, 1.0f,   1, 0 };
  pj.p[4] = { vb,   WT[2], bv,   nullptr, Vtb,  1.0f,   0, 1 };
  pj.p[5] = { posb, WT[4], bpq,  nullptr, PQs,  0.5f,   0, 0 };
  pj.p[6] = { posb, WT[3], bpk,  nullptr, PKs,  0.5f,   0, 0 };
  // 3. position projections (phases 5,6)
  proj_kernel<<<dim3(8, 4), 256, 0, stream>>>(pj, 5);
  // 4. q,k,p,m,v projections (phases 0..4)
  proj_kernel<<<dim3(20, 128), 256, 0, stream>>>(pj, 0);
  // 5. attention
  attn_kernel<<<dim3(2, 8, 32), 512, 0, stream>>>(Qraw, Praw, Kraw, Mraw, Vtb, iseq, Cb);
  // 6. output projection -> bf16
  gemm1_kernel<0><<<dim3(4, 128), 256, 0, stream>>>(Cb, WT[7], bd, db, 512, 512);
  // 7. LN1 (+ f32 x residual) -> bf16
  ln_kernel<0><<<4096, 256, 0, stream>>>(db, x, ln_g, ln_b, nullptr, ab);
  // 8. FFN1 (gelu) -> bf16
  gemm1_kernel<1><<<dim3(16, 128), 256, 0, stream>>>(ab, W1T, b1, h1b, 2048, 512);
  // 9. FFN2 -> bf16
  gemm1_kernel<0><<<dim3(4, 128), 256, 0, stream>>>(h1b, W2T, b2, f2, 512, 2048);
  // 10. LN2 (+ bf16 attn_out residual) -> f32 out
  ln_kernel<1><<<4096, 256, 0, stream>>>(f2, ab, ln2_g, ln2_b, out, nullptr);
}

// Round 2
// 501.364 us; speedup vs baseline: 1.1784x; 1.1647x over previous
//
#include <hip/hip_runtime.h>
#include <math.h>

// ============================================================================
// acsasrec_decode2 v6: v5 + T3-minimum prefetch double-buffer + T1 XCD swizzle.
//  - kloop: 2x LDS buffers (32KB). Per iter: issue next-tile global_load_lds
//    into buf^1 FIRST, then ds_read+MFMA current buf, then asm vmcnt(0) +
//    raw s_barrier (no __syncthreads full-drain before compute). Load latency
//    now hides under ds_read+MFMA instead of being serially exposed (v5
//    counters: MfmaUtil 9.5%, VALUBusy 17%, HBM 12% -- pure latency stall).
//  - T1: bijective XCD swizzle of block ids in proj/gemm1 (all grids %8==0):
//    each XCD gets contiguous m-panels x all n -> A-panel fetched once/XCD
//    (v5 FETCH 68MB vs ideal 18MB on FFN1), loads become L2-hits.
//  - T2 swizzle (v5) kept: prerequisite now that LDS reads join critical path.
//  - 10 dispatches, same numerics.
// ============================================================================

typedef unsigned short u16;
typedef __attribute__((ext_vector_type(8))) short bf16x8;
typedef __attribute__((ext_vector_type(4))) float f32x4;

#define NM 16384        // B*S tokens

__device__ __forceinline__ u16 f2b(float f) {
  union { float f; unsigned u; } x; x.f = f;
  return (u16)((x.u + 0x7fffu + ((x.u >> 16) & 1u)) >> 16);  // RNE
}
__device__ __forceinline__ float b2f(u16 u) {
  union { unsigned u; float f; } x; x.u = ((unsigned)u) << 16; return x.f;
}
__device__ __forceinline__ f32x4 mfma16(bf16x8 a, bf16x8 b, f32x4 c) {
  return __builtin_amdgcn_mfma_f32_16x16x32_bf16(a, b, c, 0, 0, 0);
}
// async global->LDS, 16B/lane; LDS dest = wave-uniform base + lane*16.
__device__ __forceinline__ void gl16(const u16* g, u16* l) {
  __builtin_amdgcn_global_load_lds(
      (const __attribute__((address_space(1))) unsigned int*)(const void*)g,
      (__attribute__((address_space(3))) unsigned int*)(void*)l, 16, 0, 0);
}
__device__ __forceinline__ bf16x8 baddv(bf16x8 a, bf16x8 b) {
  bf16x8 r;
  #pragma unroll
  for (int e = 0; e < 8; ++e) r[e] = (short)f2b(b2f((u16)a[e]) + b2f((u16)b[e]));
  return r;
}

// ---------------- BK=32 K-loop: prefetch dbuf + T2 swizzle -----------------
// LDS: sm = [buf0: As(4096) Bs(4096)][buf1: As Bs] u16 (32KB total).
// Tile layout linear [128][32] bf16; 16B slot s of row r holds global chunk
// g = s ^ ((r>>1)&3) (staged via pre-swizzled global source); fragment reads
// use slot = quad ^ ((l16>>1)&3)  -> conflict-free ds_read_b128.
// Schedule (T3 minimum 2-phase): prologue stages tile0; each iter issues
// tile(it+1) into buf^1, computes buf, then vmcnt(0) + s_barrier.
__device__ __forceinline__ void kloop(
    const u16* __restrict__ A, const u16* __restrict__ W,
    int m0, int n0, int K, int kiters, u16* sm, bool vres,
    f32x4 (&acc)[4][4])
{
  const int tid = threadIdx.x;
  const int wave = tid>>6, lane = tid&63, quad = lane>>4, l16 = lane&15;
  const int wm = wave>>1, wn = wave&1;
  const int r1 = tid>>2;
  const int ch1 = (((tid&3) ^ ((r1>>1)&3)) << 3);  // swizzled source chunk (elems)
  const int qsw = ((quad ^ ((l16>>1)&3)) << 3);    // swizzled read column (elems)
  const u16* pA = A + (size_t)(m0+r1)*K + ch1;
  const u16* pB = W + (size_t)(n0+r1)*K + ch1;
  u16* s0 = sm + tid*8;
  // prologue: stage tile 0 into buf0
  gl16(pA, s0);              gl16(pA + (size_t)64*K, s0 + 2048);
  gl16(pB, s0 + 4096);       gl16(pB + (size_t)64*K, s0 + 6144);
  asm volatile("s_waitcnt vmcnt(0)" ::: "memory");
  __builtin_amdgcn_s_barrier();
  int buf = 0;
  for (int it = 0; it < kiters; ++it) {
    if (it + 1 < kiters) {   // prefetch next tile into buf^1 (stays in flight)
      const int kn = (it + 1)*32;
      u16* sn = s0 + (buf^1)*8192;
      gl16(pA + kn, sn);           gl16(pA + (size_t)64*K + kn, sn + 2048);
      gl16(pB + kn, sn + 4096);    gl16(pB + (size_t)64*K + kn, sn + 6144);
    }
    const u16* As = sm + buf*8192;
    const u16* Bs = As + 4096;
    bf16x8 af[4], bf[4];
    #pragma unroll
    for (int i = 0; i < 4; ++i)
      af[i] = *(const bf16x8*)&As[(wm*64 + i*16 + l16)*32 + qsw];
    #pragma unroll
    for (int j = 0; j < 4; ++j)
      bf[j] = *(const bf16x8*)&Bs[(wn*64 + j*16 + l16)*32 + qsw];
    if (vres) {     // value residual from staged A-tile (N==K==512 space)
      const int k0 = it*32;
      #pragma unroll
      for (int j = 0; j < 4; ++j) {
        const int start = n0 + wn*64 + j*16;
        if ((start & ~31) == k0) {
          const int c = (start & 31) + l16;
          #pragma unroll
          for (int i = 0; i < 4; ++i)
            #pragma unroll
            for (int rr = 0; rr < 4; ++rr) {
              const int rw = wm*64 + i*16 + quad*4 + rr;
              const int sw = ((((c>>3) ^ ((rw>>1)&3)) << 3) | (c & 7));
              acc[i][j][rr] += b2f(As[rw*32 + sw]);
            }
        }
      }
    }
    #pragma unroll
    for (int i = 0; i < 4; ++i)
      #pragma unroll
      for (int j = 0; j < 4; ++j)
        acc[i][j] = mfma16(af[i], bf[j], acc[i][j]);
    asm volatile("s_waitcnt vmcnt(0)" ::: "memory");  // next tile landed
    __builtin_amdgcn_s_barrier();                     // all waves done w/ buf
    buf ^= 1;
  }
}

// ---------------- standard epilogue: acc -> LDS bf16 tile -> 16B stores -----
// out[M,N] bf16; v = (acc + bias [gelu]) [+ex] * scale.
// exmode: 0 none | 1 ex[(gr%512)*512+gc] | 2 ex[gr*512+gc]  (ex is bf16)
__device__ __forceinline__ void epi_std(
    f32x4 (&acc)[4][4], const float* __restrict__ bias,
    const u16* __restrict__ ex, int exmode, float scale, int gelu,
    u16* __restrict__ out, int m0, int n0, int N, u16* til)
{
  const int tid = threadIdx.x;
  const int wave = tid>>6, lane = tid&63, quad = lane>>4, l16 = lane&15;
  const int wm = wave>>1, wn = wave&1;
  #pragma unroll
  for (int pass = 0; pass < 2; ++pass) {
    if (wm == pass) {
      #pragma unroll
      for (int j = 0; j < 4; ++j) {
        const int c = wn*64 + j*16 + l16;
        const float bv = bias[n0 + c];
        #pragma unroll
        for (int i = 0; i < 4; ++i)
          #pragma unroll
          for (int rr = 0; rr < 4; ++rr) {
            float v = acc[i][j][rr] + bv;
            if (gelu) v = 0.5f*v*(1.0f + erff(v*0.70710678118654752f));
            til[(i*16 + quad*4 + rr)*136 + c] = f2b(v);
          }
      }
    }
    __syncthreads();
    const int r = tid>>2, ck = tid&3;
    const int gr = m0 + pass*64 + r;
    #pragma unroll
    for (int kk = 0; kk < 4; ++kk) {
      const int cc = ck*32 + kk*8, gc = n0 + cc;
      u16 e8[8];
      *(uint4*)e8 = *(const uint4*)&til[r*136 + cc];
      if (exmode) {
        const u16* ep = (exmode == 1) ? &ex[(size_t)(gr & 511)*512 + gc]
                                      : &ex[(size_t)gr*512 + gc];
        #pragma unroll
        for (int e = 0; e < 8; ++e) e8[e] = f2b((b2f(e8[e]) + b2f(ep[e]))*scale);
      } else if (scale != 1.0f) {
        #pragma unroll
        for (int e = 0; e < 8; ++e) e8[e] = f2b(b2f(e8[e])*scale);
      }
      *(uint4*)&out[(size_t)gr*N + gc] = *(uint4*)e8;
    }
    __syncthreads();
  }
}

// ---------------- V epilogue: transposed store -> Vt[B*8*64, 512] ----------
__device__ __forceinline__ void epi_vt(
    f32x4 (&acc)[4][4], const float* __restrict__ bias,
    u16* __restrict__ Vt, int m0, int n0, u16* til)
{
  const int tid = threadIdx.x;
  const int wave = tid>>6, lane = tid&63, quad = lane>>4, l16 = lane&15;
  const int wm = wave>>1, wn = wave&1;
  const int b = m0 >> 9, s0 = m0 & 511;
  #pragma unroll
  for (int pass = 0; pass < 2; ++pass) {
    if (wn == pass) {
      #pragma unroll
      for (int j = 0; j < 4; ++j) {
        const int cl = j*16 + l16;                 // 0..63
        const float bv = bias[n0 + pass*64 + cl];
        #pragma unroll
        for (int i = 0; i < 4; ++i)
          #pragma unroll
          for (int rr = 0; rr < 4; ++rr)
            til[cl*136 + wm*64 + i*16 + quad*4 + rr] = f2b(acc[i][j][rr] + bv);
      }
    }
    __syncthreads();
    const int cl = tid>>2, ck = tid&3;
    const int gn = n0 + pass*64 + cl, h = gn>>6, d = gn&63;
    u16* orow = Vt + ((size_t)((b*8 + h)*64 + d))*512 + s0 + ck*32;
    #pragma unroll
    for (int kk = 0; kk < 4; ++kk)
      *(uint4*)&orow[kk*8] = *(const uint4*)&til[cl*136 + ck*32 + kk*8];
    __syncthreads();
  }
}

// ---------------- projection kernel (7 phases, N=K=512) ----------------
// phases: 0 q(x@Wq *0.125) 1 k(x@Wk) 2 p(bb@.5Wbq +PQs, *0.125)
//         3 m(bb@.5Wbk +PKs) 4 v(vb@Wv +vb residual -> Vt transposed)
//         5 posq(pos@Wpq *0.5 -> PQs) 6 posk(pos@Wpk *0.5 -> PKs)
struct PJ { const u16* A; const u16* W; const float* bias; const u16* ex;
            u16* out; float scale; int exmode; int epiv; };
struct ProjArgs { PJ p[7]; };

__global__ __launch_bounds__(256, 2) void proj_kernel(ProjArgs pa, int phaseBase) {
  __shared__ __align__(16) u16 smem[16384];   // 2x(As+Bs) dbuf; til reuse
  const int nbx = gridDim.x;
  const int nwg = nbx * gridDim.y;
  int lin = blockIdx.y*nbx + blockIdx.x;       // dispatch-order linear id
  lin = (lin & 7)*(nwg >> 3) + (lin >> 3);     // T1: XCD k -> contiguous chunk
  const int bx = lin % nbx, by = lin / nbx;
  const PJ P = pa.p[phaseBase + (bx >> 2)];
  const int n0 = (bx & 3)*128, m0 = by*128;
  f32x4 acc[4][4] = {};
  kloop(P.A, P.W, m0, n0, 512, 16, smem, P.epiv != 0, acc);
  if (P.epiv) epi_vt(acc, P.bias, P.out, m0, n0, smem);
  else        epi_std(acc, P.bias, P.ex, P.exmode, P.scale, 0, P.out, m0, n0, 512, smem);
}

// ---------------- single GEMM (d-proj, FFN1, FFN2) ----------------
template<int GELU>
__global__ __launch_bounds__(256, 2) void gemm1_kernel(
    const u16* __restrict__ A, const u16* __restrict__ W,
    const float* __restrict__ bias, u16* __restrict__ out, int N, int K)
{
  __shared__ __align__(16) u16 smem[16384];
  const int nbx = gridDim.x;
  const int nwg = nbx * gridDim.y;
  int lin = blockIdx.y*nbx + blockIdx.x;
  lin = (lin & 7)*(nwg >> 3) + (lin >> 3);     // T1 XCD swizzle
  const int m0 = (lin / nbx)*128, n0 = (lin % nbx)*128;
  f32x4 acc[4][4] = {};
  kloop(A, W, m0, n0, K, K>>5, smem, false, acc);
  epi_std(acc, bias, nullptr, 0, 1.0f, GELU, out, m0, n0, N, smem);
}

// ---------------- cast f32 -> bf16 (all inputs) ----------------
__global__ __launch_bounds__(256) void cast_all_kernel(
    const float* __restrict__ x, const float* __restrict__ v,
    const float* __restrict__ be, const float* __restrict__ pos,
    u16* __restrict__ xb, u16* __restrict__ vb, u16* __restrict__ bb,
    u16* __restrict__ posb)
{
  int z = blockIdx.y;
  const float* in = (z==0) ? x : (z==1) ? v : (z==2) ? be : pos;
  u16* out = (z==0) ? xb : (z==1) ? vb : (z==2) ? bb : posb;
  int n4 = (z < 3) ? (NM*512/4) : (512*512/4);
  int i = blockIdx.x*256 + threadIdx.x;
  if (i >= n4) return;
  float4 w = ((const float4*)in)[i];
  ((ushort4*)out)[i] = make_ushort4(f2b(w.x), f2b(w.y), f2b(w.z), f2b(w.w));
}

// ---------------- weight prep: transpose+cast 10 weights + biases ----------
struct PrepArgs {
  const float* w[10];  // Wq Wk Wv Wpk Wpq Wbk Wbq Wd W1 W2
  u16* o[10];
  const float* bbq; const float* bbk;
  float* Bq2; float* Bk2;
};
__global__ __launch_bounds__(256) void wprep_all_kernel(PrepArgs a) {
  int job = blockIdx.x;
  if (job == 1024) {   // Bq2 = 0.5*bbq ; Bk2 = 0.5*bbk
    for (int i = threadIdx.x; i < 512; i += 256) {
      a.Bq2[i] = 0.5f*a.bbq[i];
      a.Bk2[i] = 0.5f*a.bbk[i];
    }
    return;
  }
  int wsel, n0, k0, K, N;
  if (job < 512)      { wsel = job>>6; int t = job&63;  n0=(t&7)*64;  k0=(t>>3)*64; K=512;  N=512; }
  else if (job < 768) { wsel = 8;      int t = job-512; n0=(t&31)*64; k0=(t>>5)*64; K=512;  N=2048; }
  else                { wsel = 9;      int t = job-768; n0=(t&7)*64;  k0=(t>>3)*64; K=2048; N=512; }
  float sc = (wsel == 5 || wsel == 6) ? 0.5f : 1.0f;    // Wbk, Wbq pre-scaled
  const float* in = a.w[wsel];
  u16* out = a.o[wsel];
  __shared__ __align__(16) u16 til[64*72];
  for (int idx = threadIdx.x; idx < 4096; idx += 256) {
    int r = idx>>6, c = idx&63;
    til[r*72+c] = f2b(in[(size_t)(k0+r)*N + n0+c] * sc);
  }
  __syncthreads();
  for (int idx = threadIdx.x; idx < 4096; idx += 256) {
    int r = idx>>6, c = idx&63;
    out[(size_t)(n0+r)*K + k0+c] = til[c*72+r];
  }
}

// ---------------- flash attention v4 ----------------
// grid (qh=2, h=8, b=32); 512 threads; 2 q-strips/wave = 256 q-rows/block.
// Q-frags: [q+p | q] combined in-register from Qraw/Praw (both pre-scaled /8).
// K-LDS: [k | m] staged from Kraw/Mraw. No-max softmax (masked = exp*1e-30).
__global__ __launch_bounds__(512, 2) void attn_kernel(
    const u16* __restrict__ Qraw, const u16* __restrict__ Praw,
    const u16* __restrict__ Kraw, const u16* __restrict__ Mraw,
    const u16* __restrict__ Vt, const int* __restrict__ iseq,
    u16* __restrict__ ctx)
{
  const int qh = blockIdx.x, h = blockIdx.y, b = blockIdx.z;
  const int tid = threadIdx.x;
  const int wave = tid>>6, lane = tid&63, quad = lane>>4, l16 = lane&15;

  __shared__ __align__(16) u16 Ks[2][64*136];
  __shared__ __align__(16) u16 Vs[2][64*72];
  __shared__ __align__(16) u16 Ps[8][16*72];
  __shared__ float sel[512];

  const int q0 = qh*256;
  const int ntiles = 4*qh + 4;
  const u16* Kg = Kraw + (size_t)(b*512)*512 + h*64;
  const u16* Mg = Mraw + (size_t)(b*512)*512 + h*64;
  const u16* Vg = Vt + (size_t)((b*8 + h)*64)*512;

  if (tid < 512) sel[tid] = (iseq[b*512 + tid] > 0) ? 1.0f : 1e-30f;

  bf16x8 aq[2][4];
  #pragma unroll
  for (int s = 0; s < 2; ++s) {
    const size_t ro = (size_t)(b*512 + q0 + s*128 + wave*16 + l16)*512 + h*64;
    bf16x8 qf0 = *(const bf16x8*)&Qraw[ro + quad*8];
    bf16x8 qf1 = *(const bf16x8*)&Qraw[ro + 32 + quad*8];
    bf16x8 pf0 = *(const bf16x8*)&Praw[ro + quad*8];
    bf16x8 pf1 = *(const bf16x8*)&Praw[ro + 32 + quad*8];
    aq[s][0] = baddv(qf0, pf0); aq[s][1] = baddv(qf1, pf1);
    aq[s][2] = qf0;             aq[s][3] = qf1;
  }

  const int sr = tid>>3, sc8 = (tid&7)*8;
  uint4 kreg = *(const uint4*)&Kg[(size_t)sr*512 + sc8];
  uint4 mreg = *(const uint4*)&Mg[(size_t)sr*512 + sc8];
  uint4 vreg = *(const uint4*)&Vg[(size_t)sr*512 + sc8];

  f32x4 Ob[2][4] = {};
  float lrow[2][4] = {};
  u16* Pw = Ps[wave];
  int buf = 0;

  for (int kt = 0; kt < ntiles; ++kt) {
    const int k0 = kt*64;
    *(uint4*)&Ks[buf][sr*136 + sc8]      = kreg;
    *(uint4*)&Ks[buf][sr*136 + 64 + sc8] = mreg;
    *(uint4*)&Vs[buf][sr*72 + sc8]       = vreg;
    __syncthreads();
    if (kt + 1 < ntiles) {
      const int kn = k0 + 64;
      kreg = *(const uint4*)&Kg[(size_t)(kn + sr)*512 + sc8];
      mreg = *(const uint4*)&Mg[(size_t)(kn + sr)*512 + sc8];
      vreg = *(const uint4*)&Vg[(size_t)sr*512 + kn + sc8];
    }
    const bool act0 = (q0 + wave*16 + 15) >= k0;
    const bool act1 = (q0 + 128 + wave*16 + 15) >= k0;
    if (act1) {
      f32x4 sc[2][4] = {};
      #pragma unroll
      for (int ks = 0; ks < 4; ++ks) {
        bf16x8 bk[4];
        #pragma unroll
        for (int j = 0; j < 4; ++j)
          bk[j] = *(const bf16x8*)&Ks[buf][(j*16 + l16)*136 + ks*32 + quad*8];
        if (act0) {
          #pragma unroll
          for (int j = 0; j < 4; ++j) sc[0][j] = mfma16(aq[0][ks], bk[j], sc[0][j]);
        }
        #pragma unroll
        for (int j = 0; j < 4; ++j) sc[1][j] = mfma16(aq[1][ks], bk[j], sc[1][j]);
      }
      #pragma unroll
      for (int s = 0; s < 2; ++s) {
        if (s == 0 && !act0) continue;
        const int rb = q0 + s*128 + wave*16 + quad*4;
        float pj[4][4];
        #pragma unroll
        for (int j = 0; j < 4; ++j) {
          int col = k0 + j*16 + l16;
          float fs = sel[col];
          #pragma unroll
          for (int r = 0; r < 4; ++r) {
            float m2 = (col <= rb + r) ? fs : 1e-30f;
            pj[j][r] = __expf(sc[s][j][r]) * m2;
          }
        }
        #pragma unroll
        for (int r = 0; r < 4; ++r)
          lrow[s][r] += pj[0][r] + pj[1][r] + pj[2][r] + pj[3][r];
        #pragma unroll
        for (int j = 0; j < 4; ++j)
          #pragma unroll
          for (int r = 0; r < 4; ++r)
            Pw[(quad*4 + r)*72 + j*16 + l16] = f2b(pj[j][r]);
        #pragma unroll
        for (int c = 0; c < 4; ++c) {
          #pragma unroll
          for (int k2 = 0; k2 < 2; ++k2) {
            bf16x8 ap = *(const bf16x8*)&Pw[l16*72 + k2*32 + quad*8];
            bf16x8 bv = *(const bf16x8*)&Vs[buf][(c*16 + l16)*72 + k2*32 + quad*8];
            Ob[s][c] = mfma16(ap, bv, Ob[s][c]);
          }
        }
      }
    }
    buf ^= 1;
  }

  #pragma unroll
  for (int s = 0; s < 2; ++s) {
    #pragma unroll
    for (int r = 0; r < 4; ++r) {
      float l = lrow[s][r];
      #pragma unroll
      for (int d2 = 1; d2 < 16; d2 <<= 1) l += __shfl_xor(l, d2, 64);
      float inv = 1.0f / l;
      int grow = b*512 + q0 + s*128 + wave*16 + quad*4 + r;
      #pragma unroll
      for (int c = 0; c < 4; ++c)
        ctx[(size_t)grow*512 + h*64 + c*16 + l16] = f2b(Ob[s][c][r]*inv);
    }
  }
}

// ---------------- LayerNorm over H=512 (bf16 main input) ----------------
// RES: 0 = f32 residual, 1 = bf16 residual.
template<int RES>
__global__ __launch_bounds__(256) void ln_kernel(
    const u16* __restrict__ a, const void* __restrict__ resv,
    const float* __restrict__ g, const float* __restrict__ be,
    float* __restrict__ of, u16* __restrict__ ob)
{
  const int wave = threadIdx.x >> 6, lane = threadIdx.x & 63;
  const int row = blockIdx.x*4 + wave;
  const ushort4* pa = (const ushort4*)(a + (size_t)row*512);
  ushort4 a0 = pa[lane], a1 = pa[lane+64];
  float v[8] = { b2f(a0.x), b2f(a0.y), b2f(a0.z), b2f(a0.w),
                 b2f(a1.x), b2f(a1.y), b2f(a1.z), b2f(a1.w) };
  if (RES == 1) {
    const ushort4* pr = (const ushort4*)((const u16*)resv + (size_t)row*512);
    ushort4 u0 = pr[lane], u1 = pr[lane+64];
    v[0]+=b2f(u0.x); v[1]+=b2f(u0.y); v[2]+=b2f(u0.z); v[3]+=b2f(u0.w);
    v[4]+=b2f(u1.x); v[5]+=b2f(u1.y); v[6]+=b2f(u1.z); v[7]+=b2f(u1.w);
  } else {
    const float4* pr = (const float4*)((const float*)resv + (size_t)row*512);
    float4 r0 = pr[lane], r1 = pr[lane+64];
    v[0]+=r0.x; v[1]+=r0.y; v[2]+=r0.z; v[3]+=r0.w;
    v[4]+=r1.x; v[5]+=r1.y; v[6]+=r1.z; v[7]+=r1.w;
  }
  float s = 0.f, q = 0.f;
  #pragma unroll
  for (int e = 0; e < 8; ++e) { s += v[e]; q += v[e]*v[e]; }
  #pragma unroll
  for (int d = 1; d < 64; d <<= 1) { s += __shfl_xor(s, d, 64); q += __shfl_xor(q, d, 64); }
  float mean = s * (1.0f/512.0f);
  float var  = q * (1.0f/512.0f) - mean*mean;
  float rstd = rsqrtf(var + 1e-12f);
  float4 g0 = ((const float4*)g)[lane],  g1 = ((const float4*)g)[lane+64];
  float4 b0 = ((const float4*)be)[lane], b1 = ((const float4*)be)[lane+64];
  float o[8];
  o[0]=(v[0]-mean)*rstd*g0.x+b0.x; o[1]=(v[1]-mean)*rstd*g0.y+b0.y;
  o[2]=(v[2]-mean)*rstd*g0.z+b0.z; o[3]=(v[3]-mean)*rstd*g0.w+b0.w;
  o[4]=(v[4]-mean)*rstd*g1.x+b1.x; o[5]=(v[5]-mean)*rstd*g1.y+b1.y;
  o[6]=(v[6]-mean)*rstd*g1.z+b1.z; o[7]=(v[7]-mean)*rstd*g1.w+b1.w;
  if (of) {
    ((float4*)(of + (size_t)row*512))[lane]    = make_float4(o[0],o[1],o[2],o[3]);
    ((float4*)(of + (size_t)row*512))[lane+64] = make_float4(o[4],o[5],o[6],o[7]);
  }
  if (ob) {
    ((ushort4*)(ob + (size_t)row*512))[lane]    = make_ushort4(f2b(o[0]),f2b(o[1]),f2b(o[2]),f2b(o[3]));
    ((ushort4*)(ob + (size_t)row*512))[lane+64] = make_ushort4(f2b(o[4]),f2b(o[5]),f2b(o[6]),f2b(o[7]));
  }
}

// ============================================================================
extern "C" void kernel_launch(void* const* d_in, const int* in_sizes, int n_in,
                              void* d_out, int out_size, void* d_ws, size_t ws_size,
                              hipStream_t stream) {
  (void)in_sizes; (void)n_in; (void)out_size; (void)ws_size;
  const float* x    = (const float*)d_in[0];
  const float* vin  = (const float*)d_in[1];
  const float* beh  = (const float*)d_in[2];
  const float* pos  = (const float*)d_in[3];
  const float* bq   = (const float*)d_in[5];
  const float* bk   = (const float*)d_in[7];
  const float* bv   = (const float*)d_in[9];
  const float* bpk  = (const float*)d_in[11];
  const float* bpq  = (const float*)d_in[13];
  const float* bbk  = (const float*)d_in[15];
  const float* bbq  = (const float*)d_in[17];
  const float* bd   = (const float*)d_in[19];
  const float* ln_g = (const float*)d_in[20];
  const float* ln_b = (const float*)d_in[21];
  const float* b1   = (const float*)d_in[23];
  const float* b2   = (const float*)d_in[25];
  const float* ln2_g= (const float*)d_in[26];
  const float* ln2_b= (const float*)d_in[27];
  const int*   iseq = (const int*)d_in[28];
  float* out = (float*)d_out;
  char* ws = (char*)d_ws;

  // ---- workspace (~145 MB) ----
  size_t off = 0;
  auto nxt = [&](size_t sz) { size_t r = off; off += (sz + 255) & ~(size_t)255; return r; };
  size_t oWT[8]; for (int i = 0; i < 8; ++i) oWT[i] = nxt(512*512*2);
  size_t oW1T = nxt((size_t)512*2048*2);
  size_t oW2T = nxt((size_t)512*2048*2);
  size_t oBq2 = nxt(512*4);
  size_t oBk2 = nxt(512*4);
  size_t oPb  = nxt(512*512*2);
  size_t oPQ  = nxt(512*512*2);           // PQs bf16
  size_t oPK  = nxt(512*512*2);           // PKs bf16
  size_t oXb  = nxt((size_t)NM*512*2);    // xb; dead after proj, reused as ab
  size_t oVb  = nxt((size_t)NM*512*2);    // vb; dead after proj, reused as Cb
  size_t oBb  = nxt((size_t)NM*512*2);    // bb
  size_t oQr  = nxt((size_t)NM*512*2);    // Qraw  (Qr..Mr contiguous 134MB; h1b after attn)
  size_t oPr  = nxt((size_t)NM*512*2);    // Praw
  size_t oKr  = nxt((size_t)NM*512*2);    // Kraw
  size_t oMr  = nxt((size_t)NM*512*2);    // Mraw
  size_t oVt  = nxt((size_t)NM*512*2);    // Vt; dead after attn, reused as f2

  u16* WT[8]; for (int i = 0; i < 8; ++i) WT[i] = (u16*)(ws + oWT[i]);
  u16*   W1T  = (u16*)(ws + oW1T);
  u16*   W2T  = (u16*)(ws + oW2T);
  float* Bq2  = (float*)(ws + oBq2);
  float* Bk2  = (float*)(ws + oBk2);
  u16*   posb = (u16*)(ws + oPb);
  u16*   PQs  = (u16*)(ws + oPQ);
  u16*   PKs  = (u16*)(ws + oPK);
  u16*   xb   = (u16*)(ws + oXb);
  u16*   vb   = (u16*)(ws + oVb);
  u16*   bb   = (u16*)(ws + oBb);
  u16*   Qraw = (u16*)(ws + oQr);
  u16*   Praw = (u16*)(ws + oPr);
  u16*   Kraw = (u16*)(ws + oKr);
  u16*   Mraw = (u16*)(ws + oMr);
  u16*   Vtb  = (u16*)(ws + oVt);
  u16*   Cb   = (u16*)(ws + oVb);   // alias: vb dead after proj
  u16*   db   = (u16*)(ws + oPr);   // alias: Praw dead after attn (LN1 reads before FFN1 writes h1b)
  u16*   ab   = (u16*)(ws + oXb);   // alias: xb dead after proj
  u16*   h1b  = (u16*)(ws + oQr);   // alias: Qraw..Mraw dead after attn (67 MB)
  u16*   f2   = (u16*)(ws + oVt);   // alias: Vt dead after attn

  // 1. casts
  cast_all_kernel<<<dim3(8192, 4), 256, 0, stream>>>(x, vin, beh, pos, xb, vb, bb, posb);
  // 2. weight prep + combined biases
  PrepArgs pr;
  const int wi[10] = {4, 6, 8, 10, 12, 14, 16, 18, 22, 24};
  for (int i = 0; i < 10; ++i) pr.w[i] = (const float*)d_in[wi[i]];
  for (int i = 0; i < 8; ++i)  pr.o[i] = WT[i];
  pr.o[8] = W1T; pr.o[9] = W2T;
  pr.bbq = bbq; pr.bbk = bbk; pr.Bq2 = Bq2; pr.Bk2 = Bk2;
  wprep_all_kernel<<<1025, 256, 0, stream>>>(pr);
  // phase table
  ProjArgs pj;
  pj.p[0] = { xb,   WT[0], bq,   nullptr, Qraw, 0.125f, 0, 0 };
  pj.p[1] = { xb,   WT[1], bk,   nullptr, Kraw, 1.0f,   0, 0 };
  pj.p[2] = { bb,   WT[6], Bq2,  PQs,     Praw, 0.125f, 1, 0 };
  pj.p[3] = { bb,   WT[5], Bk2,  PKs,     Mraw, 1.0f,   1, 0 };
  pj.p[4] = { vb,   WT[2], bv,   nullptr, Vtb,  1.0f,   0, 1 };
  pj.p[5] = { posb, WT[4], bpq,  nullptr, PQs,  0.5f,   0, 0 };
  pj.p[6] = { posb, WT[3], bpk,  nullptr, PKs,  0.5f,   0, 0 };
  // 3. position projections (phases 5,6)
  proj_kernel<<<dim3(8, 4), 256, 0, stream>>>(pj, 5);
  // 4. q,k,p,m,v projections (phases 0..4)
  proj_kernel<<<dim3(20, 128), 256, 0, stream>>>(pj, 0);
  // 5. attention
  attn_kernel<<<dim3(2, 8, 32), 512, 0, stream>>>(Qraw, Praw, Kraw, Mraw, Vtb, iseq, Cb);
  // 6. output projection -> bf16
  gemm1_kernel<0><<<dim3(4, 128), 256, 0, stream>>>(Cb, WT[7], bd, db, 512, 512);
  // 7. LN1 (+ f32 x residual) -> bf16
  ln_kernel<0><<<4096, 256, 0, stream>>>(db, x, ln_g, ln_b, nullptr, ab);
  // 8. FFN1 (gelu) -> bf16
  gemm1_kernel<1><<<dim3(16, 128), 256, 0, stream>>>(ab, W1T, b1, h1b, 2048, 512);
  // 9. FFN2 -> bf16
  gemm1_kernel<0><<<dim3(4, 128), 256, 0, stream>>>(h1b, W2T, b2, f2, 512, 2048);
  // 10. LN2 (+ bf16 attn_out residual) -> f32 out
  ln_kernel<1><<<4096, 256, 0, stream>>>(f2, ab, ln2_g, ln2_b, out, nullptr);
}